// Round 1
// baseline (24631.950 us; speedup 1.0000x reference)
//
#include <hip/hip_runtime.h>

typedef _Float16 f16;
typedef f16 h8 __attribute__((ext_vector_type(8)));
typedef float f4 __attribute__((ext_vector_type(4)));

#define ROWS 32
#define HH 256
#define TT 200
#define NTHR 512

__device__ __forceinline__ f4 mfma16(h8 a, h8 b, f4 c) {
  return __builtin_amdgcn_mfma_f32_16x16x32_f16(a, b, c, 0, 0, 0);
}
__device__ __forceinline__ f4 fzero() { f4 z; z[0]=0.f; z[1]=0.f; z[2]=0.f; z[3]=0.f; return z; }
__device__ __forceinline__ float sigm(float x) { return 1.0f / (1.0f + __expf(-x)); }
__device__ __forceinline__ float tanhfast(float x) {
  float t = __expf(-2.0f * fabsf(x));
  float r = (1.0f - t) / (1.0f + t);
  return copysignf(r, x);
}
// swizzled f16 [32][256] LDS tile: 16B chunks XORed by row&7 -> conflict-free ds_read_b128
__device__ __forceinline__ void hstore(f16* hs, int r, int d, f16 v) {
  hs[r * HH + ((((d >> 3) ^ (r & 7)) << 3) | (d & 7))] = v;
}
__device__ __forceinline__ h8 hload8(const f16* hs, int r, int kc) {
  return ((const h8*)hs)[r * 32 + (kc ^ (r & 7))];
}

// Pre-convert + fragment-order swizzle the 4 streamed weight matrices to f16 in ws.
// Layout per matrix: [n_tile][k_chunk(32)][row_in_tile(16)] of h8 -> 1KB contiguous per wave B-frag load.
__global__ void conv_w(const float* __restrict__ whh0, const float* __restrict__ wih1,
                       const float* __restrict__ whh1, const float* __restrict__ ow1,
                       f16* __restrict__ dst) {
  int i = blockIdx.x * 256 + threadIdx.x;  // 0 .. 819199
  const float* src;
  int base;
  if (i < 262144)      { src = whh0; base = 0; }
  else if (i < 524288) { src = wih1; base = 262144; }
  else if (i < 786432) { src = whh1; base = 524288; }
  else                 { src = ow1;  base = 786432; }
  int e = i - base;
  int row = e >> 8, col = e & 255;
  int idx = base + ((((row >> 4) << 5) + (col >> 3)) << 7) + ((row & 15) << 3) + (col & 7);
  dst[idx] = (f16)src[e];
}

// per-wave GEMM over its 2 h-col-tiles x 4 gate tiles x 2 m-tiles, K=256
#define GEMM_QK(ACC, HSRC, WMAT)                                                        \
  _Pragma("unroll")                                                                     \
  for (int k = 0; k < 8; ++k) {                                                         \
    h8 a0 = hload8(HSRC, lr, (k << 2) + lg);                                            \
    h8 a1 = hload8(HSRC, 16 + lr, (k << 2) + lg);                                       \
    _Pragma("unroll")                                                                   \
    for (int hi = 0; hi < 2; ++hi) {                                                    \
      _Pragma("unroll")                                                                 \
      for (int g = 0; g < 4; ++g) {                                                     \
        h8 b = WMAT[(((g << 4) + 2 * wv + hi) << 9) + (((k << 2) + lg) << 4) + lr];     \
        ACC[hi][g][0] = mfma16(a0, b, ACC[hi][g][0]);                                   \
        ACC[hi][g][1] = mfma16(a1, b, ACC[hi][g][1]);                                   \
      }                                                                                 \
    }                                                                                   \
  }

__global__ __launch_bounds__(NTHR, 2)
void traj_kernel(const float* __restrict__ x,
                 const float* __restrict__ ew1, const float* __restrict__ eb1,
                 const float* __restrict__ ew2, const float* __restrict__ eb2,
                 const float* __restrict__ ew3, const float* __restrict__ eb3,
                 const float* __restrict__ hiw, const float* __restrict__ hib,
                 const float* __restrict__ ciw, const float* __restrict__ cib,
                 const float* __restrict__ wih0,
                 const float* __restrict__ bih0, const float* __restrict__ bhh0,
                 const float* __restrict__ bih1, const float* __restrict__ bhh1,
                 const float* __restrict__ ob1, const float* __restrict__ ow2,
                 const float* __restrict__ ob2, const float* __restrict__ stok,
                 const f16* __restrict__ wk, float* __restrict__ out)
{
  __shared__ __align__(16) f16 h0s[ROWS * HH];   // 16 KB (swizzled f16 h-state / plain e-buffer)
  __shared__ __align__(16) f16 h1s[ROWS * HH];   // 16 KB
  __shared__ float o1s[ROWS * 132];              // 16.9 KB (padded stride vs bank conflicts)
  __shared__ f16 wih0s[1024 * 3];                // 6 KB
  __shared__ f16 b0s[1024];                      // 2 KB  (b_ih0 + b_hh0)
  __shared__ f16 b1s[1024];                      // 2 KB
  __shared__ float w2s[3 * 128];                 // 1.5 KB
  __shared__ float ob1s[128];
  __shared__ float decs[ROWS * 3];
  __shared__ float ob2s[4];

  const int tid  = threadIdx.x;
  const int wv   = tid >> 6;
  const int lane = tid & 63;
  const int lr   = lane & 15;
  const int lg   = lane >> 4;
  const int row0 = blockIdx.x * ROWS;

  const h8* W0  = (const h8*)wk;                 // w_hh0  [1024][256] frag-order
  const h8* W1i = (const h8*)(wk + 262144);      // w_ih1
  const h8* W1h = (const h8*)(wk + 524288);      // w_hh1
  const h8* OW1 = (const h8*)(wk + 786432);      // out_w1 [128][256]

  // ---- stage small constants ----
  for (int i = tid; i < 3072; i += NTHR) wih0s[i] = (f16)wih0[i];
  for (int i = tid; i < 1024; i += NTHR) {
    b0s[i] = (f16)(bih0[i] + bhh0[i]);
    b1s[i] = (f16)(bih1[i] + bhh1[i]);
  }
  for (int i = tid; i < 384; i += NTHR) w2s[i] = ow2[i];
  if (tid < 128) ob1s[tid] = ob1[tid];
  if (tid < 96)  decs[tid] = stok[tid % 3];
  if (tid < 3)   ob2s[tid] = ob2[tid];
  __syncthreads();

  // ---------------- encoder (one-time, fp32 VALU, e buffers plain-indexed f16) ----------------
  {
    const int r  = tid >> 4;
    const int cb = (tid & 15) << 4;
    float xr[7];
    #pragma unroll
    for (int k = 0; k < 7; ++k) xr[k] = x[(row0 + r) * 7 + k];
    for (int c16 = 0; c16 < 16; ++c16) {           // e1 -> h1s
      int c = cb + c16;
      float a = eb1[c];
      #pragma unroll
      for (int k = 0; k < 7; ++k) a += xr[k] * ew1[c * 7 + k];
      h1s[r * HH + c] = (f16)fmaxf(a, 0.0f);
    }
    __syncthreads();
    const f4* W2v = (const f4*)ew2;
    for (int c16 = 0; c16 < 16; ++c16) {           // e2 -> h0s
      int c = cb + c16;
      float a = eb2[c];
      for (int k4 = 0; k4 < 64; ++k4) {
        f4 w4 = W2v[c * 64 + k4];
        a += (float)h1s[r * HH + 4 * k4 + 0] * w4[0];
        a += (float)h1s[r * HH + 4 * k4 + 1] * w4[1];
        a += (float)h1s[r * HH + 4 * k4 + 2] * w4[2];
        a += (float)h1s[r * HH + 4 * k4 + 3] * w4[3];
      }
      h0s[r * HH + c] = (f16)fmaxf(a, 0.0f);
    }
    __syncthreads();
    const f4* W3v = (const f4*)ew3;
    for (int c16 = 0; c16 < 16; ++c16) {           // e3 -> h1s
      int c = cb + c16;
      float a = eb3[c];
      for (int k4 = 0; k4 < 64; ++k4) {
        f4 w4 = W3v[c * 64 + k4];
        a += (float)h0s[r * HH + 4 * k4 + 0] * w4[0];
        a += (float)h0s[r * HH + 4 * k4 + 1] * w4[1];
        a += (float)h0s[r * HH + 4 * k4 + 2] * w4[2];
        a += (float)h0s[r * HH + 4 * k4 + 3] * w4[3];
      }
      h1s[r * HH + c] = (f16)fmaxf(a, 0.0f);
    }
    __syncthreads();
  }

  // ---------------- h/c init from e3 (in h1s, plain layout) ----------------
  float c0v[2][2][4], c1v[2][2][4];
  float h1st[2][8];
  {
    const f4* HIW4 = (const f4*)hiw;
    const f4* CIW4 = (const f4*)ciw;
    #pragma unroll
    for (int hi = 0; hi < 2; ++hi) {
      const int d = ((2 * wv + hi) << 4) + lr;
      float aH0[8], aC0[8], aH1[8], aC1[8];
      #pragma unroll
      for (int ri = 0; ri < 8; ++ri) { aH0[ri] = 0.f; aC0[ri] = 0.f; aH1[ri] = 0.f; aC1[ri] = 0.f; }
      for (int k4 = 0; k4 < 64; ++k4) {
        f4 wh0 = HIW4[d * 64 + k4];
        f4 wc0 = CIW4[d * 64 + k4];
        f4 wh1 = HIW4[(256 + d) * 64 + k4];
        f4 wc1 = CIW4[(256 + d) * 64 + k4];
        #pragma unroll
        for (int ri = 0; ri < 8; ++ri) {
          const int r = ((ri >> 2) << 4) + (lg << 2) + (ri & 3);
          #pragma unroll
          for (int j = 0; j < 4; ++j) {
            float ev = (float)h1s[r * HH + 4 * k4 + j];
            aH0[ri] += ev * wh0[j];
            aC0[ri] += ev * wc0[j];
            aH1[ri] += ev * wh1[j];
            aC1[ri] += ev * wc1[j];
          }
        }
      }
      const float bh0 = hib[d], bc0 = cib[d], bh1v = hib[256 + d], bc1 = cib[256 + d];
      #pragma unroll
      for (int ri = 0; ri < 8; ++ri) {
        c0v[hi][ri >> 2][ri & 3] = aC0[ri] + bc0;
        c1v[hi][ri >> 2][ri & 3] = aC1[ri] + bc1;
        h1st[hi][ri] = aH1[ri] + bh1v;
      }
      // h0s holds dead e2 -> write swizzled h0 now
      #pragma unroll
      for (int ri = 0; ri < 8; ++ri) {
        const int r = ((ri >> 2) << 4) + (lg << 2) + (ri & 3);
        hstore(h0s, r, d, (f16)(aH0[ri] + bh0));
      }
    }
  }
  __syncthreads();  // all e3 reads of h1s done
  #pragma unroll
  for (int hi = 0; hi < 2; ++hi) {
    const int d = ((2 * wv + hi) << 4) + lr;
    #pragma unroll
    for (int ri = 0; ri < 8; ++ri) {
      const int r = ((ri >> 2) << 4) + (lg << 2) + (ri & 3);
      hstore(h1s, r, d, (f16)h1st[hi][ri]);
    }
  }
  __syncthreads();

  // ---------------- T = 200 sequential decoder steps ----------------
  for (int t = 0; t < TT; ++t) {
    // ---- layer 0: gates = h0 @ w_hh0^T (MFMA) ----
    f4 acc[2][4][2];
    #pragma unroll
    for (int hi = 0; hi < 2; ++hi)
      #pragma unroll
      for (int g = 0; g < 4; ++g)
        #pragma unroll
        for (int m = 0; m < 2; ++m) acc[hi][g][m] = fzero();
    GEMM_QK(acc, h0s, W0);
    __syncthreads();

    // ---- layer 0 elementwise: + dec @ w_ih0^T + biases -> LSTM cell ----
    #pragma unroll
    for (int hi = 0; hi < 2; ++hi) {
      const int col = ((2 * wv + hi) << 4) + lr;
      float wI[3], wF[3], wG[3], wO[3];
      #pragma unroll
      for (int k = 0; k < 3; ++k) {
        wI[k] = (float)wih0s[col * 3 + k];
        wF[k] = (float)wih0s[(256 + col) * 3 + k];
        wG[k] = (float)wih0s[(512 + col) * 3 + k];
        wO[k] = (float)wih0s[(768 + col) * 3 + k];
      }
      const float bI = (float)b0s[col], bF = (float)b0s[256 + col],
                  bG = (float)b0s[512 + col], bO = (float)b0s[768 + col];
      #pragma unroll
      for (int m = 0; m < 2; ++m) {
        #pragma unroll
        for (int i = 0; i < 4; ++i) {
          const int r = (m << 4) + (lg << 2) + i;
          const float d0 = decs[r * 3 + 0], d1 = decs[r * 3 + 1], d2 = decs[r * 3 + 2];
          float gI = acc[hi][0][m][i] + bI + d0 * wI[0] + d1 * wI[1] + d2 * wI[2];
          float gF = acc[hi][1][m][i] + bF + d0 * wF[0] + d1 * wF[1] + d2 * wF[2];
          float gG = acc[hi][2][m][i] + bG + d0 * wG[0] + d1 * wG[1] + d2 * wG[2];
          float gO = acc[hi][3][m][i] + bO + d0 * wO[0] + d1 * wO[1] + d2 * wO[2];
          float cn = sigm(gF) * c0v[hi][m][i] + sigm(gI) * tanhfast(gG);
          c0v[hi][m][i] = cn;
          hstore(h0s, r, col, (f16)(sigm(gO) * tanhfast(cn)));
        }
      }
    }
    __syncthreads();

    // ---- layer 1: gates = h0n @ w_ih1^T + h1 @ w_hh1^T ----
    f4 acc1[2][4][2];
    #pragma unroll
    for (int hi = 0; hi < 2; ++hi)
      #pragma unroll
      for (int g = 0; g < 4; ++g)
        #pragma unroll
        for (int m = 0; m < 2; ++m) acc1[hi][g][m] = fzero();
    GEMM_QK(acc1, h0s, W1i);
    GEMM_QK(acc1, h1s, W1h);
    __syncthreads();

    // ---- layer 1 elementwise ----
    #pragma unroll
    for (int hi = 0; hi < 2; ++hi) {
      const int col = ((2 * wv + hi) << 4) + lr;
      const float bI = (float)b1s[col], bF = (float)b1s[256 + col],
                  bG = (float)b1s[512 + col], bO = (float)b1s[768 + col];
      #pragma unroll
      for (int m = 0; m < 2; ++m) {
        #pragma unroll
        for (int i = 0; i < 4; ++i) {
          const int r = (m << 4) + (lg << 2) + i;
          float gI = acc1[hi][0][m][i] + bI;
          float gF = acc1[hi][1][m][i] + bF;
          float gG = acc1[hi][2][m][i] + bG;
          float gO = acc1[hi][3][m][i] + bO;
          float cn = sigm(gF) * c1v[hi][m][i] + sigm(gI) * tanhfast(gG);
          c1v[hi][m][i] = cn;
          hstore(h1s, r, col, (f16)(sigm(gO) * tanhfast(cn)));
        }
      }
    }
    __syncthreads();

    // ---- out head: o1 = relu(h1n @ out_w1^T + b) ----
    f4 oa0 = fzero(), oa1 = fzero();
    #pragma unroll
    for (int k = 0; k < 8; ++k) {
      h8 a0 = hload8(h1s, lr, (k << 2) + lg);
      h8 a1 = hload8(h1s, 16 + lr, (k << 2) + lg);
      h8 b = OW1[(wv << 9) + (((k << 2) + lg) << 4) + lr];
      oa0 = mfma16(a0, b, oa0);
      oa1 = mfma16(a1, b, oa1);
    }
    {
      const float obv = ob1s[(wv << 4) + lr];
      #pragma unroll
      for (int m = 0; m < 2; ++m)
        #pragma unroll
        for (int i = 0; i < 4; ++i) {
          const int r = (m << 4) + (lg << 2) + i;
          float v = (m ? oa1[i] : oa0[i]) + obv;
          o1s[r * 132 + (wv << 4) + lr] = fmaxf(v, 0.0f);
        }
    }
    __syncthreads();

    // ---- final: out = o1 @ out_w2^T + b2 ; feed back as dec ----
    if (tid < 96) {
      const int r = tid / 3, c = tid - 3 * (tid / 3);
      float a = ob2s[c];
      for (int k = 0; k < 128; ++k) a += o1s[r * 132 + k] * w2s[c * 128 + k];
      out[((size_t)(row0 + r) * TT + t) * 3 + c] = a;
      decs[r * 3 + c] = a;
    }
    __syncthreads();
  }
}

extern "C" void kernel_launch(void* const* d_in, const int* in_sizes, int n_in,
                              void* d_out, int out_size, void* d_ws, size_t ws_size,
                              hipStream_t stream) {
  (void)in_sizes; (void)n_in; (void)out_size; (void)ws_size;
  f16* wk = (f16*)d_ws;
  conv_w<<<3200, 256, 0, stream>>>((const float*)d_in[12], (const float*)d_in[15],
                                   (const float*)d_in[16], (const float*)d_in[19], wk);
  traj_kernel<<<256, NTHR, 0, stream>>>(
      (const float*)d_in[0],
      (const float*)d_in[1],  (const float*)d_in[2],
      (const float*)d_in[3],  (const float*)d_in[4],
      (const float*)d_in[5],  (const float*)d_in[6],
      (const float*)d_in[7],  (const float*)d_in[8],
      (const float*)d_in[9],  (const float*)d_in[10],
      (const float*)d_in[11],
      (const float*)d_in[13], (const float*)d_in[14],
      (const float*)d_in[17], (const float*)d_in[18],
      (const float*)d_in[20], (const float*)d_in[21],
      (const float*)d_in[22], (const float*)d_in[23],
      wk, (float*)d_out);
}